// Round 2
// baseline (940.669 us; speedup 1.0000x reference)
//
#include <hip/hip_runtime.h>
#include <math.h>

#define HW 512
#define NPIX (HW*HW)            // 262144
#define NB 4
#define NCIN 55
#define OUTX_SIZE (NB*55*NPIX)  // 57671680

// ws layout (float/uint offsets)
#define WA_OFF 0          // 37632 uints: [3 g][7 cb][7 step][64 lane][4] f16x2
#define WSUM_OFF 37632    // 18
#define BTSUM_OFF 37650   // 1
#define S_OFF 37664       // 1200: [600][2]
#define TM_OFF 38864      // 600
#define SBM_OFF 39464     // 600
// total 40064 floats = 157 KB of workspace

#define BY 16              // output rows per block
#define BX 32              // output cols per block
#define LROWS 28           // BY + 12 halo
#define LCOLS 48           // BX + 16 (x window [w0-8, w0+40), 16B-aligned)
#define NSTEP 7            // K-steps per (g, cb): 28 tap slots (25 real)
#define NCB 7              // channel-blocks of 8 (56 slots, 55 real)

typedef _Float16 half2v __attribute__((ext_vector_type(2)));
typedef __attribute__((ext_vector_type(8))) _Float16 f16x8;
typedef __attribute__((ext_vector_type(4))) float f32x4;

__device__ __forceinline__ uint pack_f16x2(float a, float b) {
  return __builtin_bit_cast(uint, __builtin_amdgcn_cvt_pkrtz(a, b));
}

// Weight A-fragments for mfma_f32_16x16x32_f16, per (g, cb, step):
// lane l holds A[row = l&15][k = (l>>4)*8 + j], j=0..7
//   row = oc slot (0..5 used), k -> tap = step*4 + (l>>4), ch = cb*8 + j
__global__ __launch_bounds__(1024) void prep_kernel(
    const float* __restrict__ w1, const float* __restrict__ w2, const float* __restrict__ w3,
    const float* __restrict__ wt, const float* __restrict__ bt,
    float* __restrict__ ws)
{
  const int t = threadIdx.x;
  uint* wp = (uint*)(ws + WA_OFF);
  for (int e = t; e < 3 * NCB * NSTEP * 64 * 4; e += 1024) {
    int u = e & 3;              // dword within lane's frag (2 channels)
    int rest = e >> 2;
    int lane = rest & 63;
    int idx = rest >> 6;        // (g*7 + cb)*7 + step
    int step = idx % 7;
    int cbg = idx / 7;
    int cb = cbg % 7;
    int g = cbg / 7;
    int oc = lane & 15;
    int kg = lane >> 4;
    int tap = step * 4 + kg;
    int c = cb * 8 + 2 * u;
    const float* wsrc = (g == 0) ? w1 : (g == 1) ? w2 : w3;
    float lo = 0.f, hi = 0.f;
    if (oc < 6 && tap < 25) {
      if (c < NCIN)     lo = wsrc[(oc * NCIN + c) * 25 + tap];
      if (c + 1 < NCIN) hi = wsrc[(oc * NCIN + c + 1) * 25 + tap];
    }
    wp[e] = pack_f16x2(lo, hi);
  }
  if (t < 18) {
    float s = 0.f;
    for (int o = 0; o < 36; o++) s += wt[o * 18 + t];
    ws[WSUM_OFF + t] = s;
  }
  if (t == 18) {
    float s = 0.f;
    for (int o = 0; o < 36; o++) s += bt[o];
    ws[BTSUM_OFF] = s;
  }
  for (int e = t; e < 1200; e += 1024) ws[S_OFF + e] = 0.f;
}

// Implicit-GEMM conv: per dilation group g, D[oc16][px16] += A(W)·B(X),
// K = 28 tap-slots x 8 ch per (g,cb) pass. Tap spatial shift folded into the
// per-lane LDS read address of the B fragment (1 ds_read_b128 per MFMA).
// LDS X tile: [28 rows][48 cols][8 ch] f16 (16B per pixel-cell).
__global__ __launch_bounds__(256, 4) void conv_kernel(
    const float* __restrict__ x, const uint* __restrict__ wA,
    const float* __restrict__ bias1, const float* __restrict__ bias2,
    const float* __restrict__ bias3, float* __restrict__ out)
{
  __shared__ uint xs[LROWS * LCOLS * 4];   // 21504 B
  const int tid = threadIdx.x;
  const int lane = tid & 63;
  const int wv = tid >> 6;          // wave 0..3 -> rows wv*4 .. wv*4+3
  const int h0 = blockIdx.y * BY, w0 = blockIdx.x * BX;
  const int bz = blockIdx.z;
  const int col = lane & 15;        // B/D: pixel column within n-tile
  const int kg  = lane >> 4;        // k-group: tap = step*4+kg ; D row base kg*4

  const bool interior = (h0 >= 6) && (h0 + BY + 6 <= HW) &&
                        (w0 >= 8) && (w0 + BX + 8 <= HW);

#pragma unroll 1
  for (int g = 0; g < 3; g++) {
    const int dil = g + 1;

    f32x4 acc[8];
#pragma unroll
    for (int nt = 0; nt < 8; nt++) acc[nt] = (f32x4){0.f, 0.f, 0.f, 0.f};

    // per-lane LDS dword offset per K-step (tap shift); padded taps -> 0 shift
    int stepoff[7];
#pragma unroll
    for (int s = 0; s < 7; s++) {
      int tap = s * 4 + kg;
      int dr = 0, dc = 0;
      if (tap < 25) { int q5 = tap / 5; dr = q5 - 2; dc = tap - q5 * 5 - 2; }
      stepoff[s] = ((dr * LCOLS + dc) * dil) << 2;
    }

#pragma unroll 1
    for (int cb = 0; cb < NCB; cb++) {
      const int c0 = cb * 8;
      __syncthreads();
      if (interior) {
        for (int e = tid; e < LROWS * 12; e += 256) {
          int yy = e / 12, xg = e - yy * 12;
          const float* src = x + (((size_t)(bz * NCIN + c0)) << 18)
                           + (size_t)((h0 - 6 + yy) * HW + (w0 - 8) + (xg << 2));
          float4 fz; fz.x = fz.y = fz.z = fz.w = 0.f;
          float4 f0 = (c0 + 0 < NCIN) ? *(const float4*)(src + ((size_t)0 << 18)) : fz;
          float4 f1 = (c0 + 1 < NCIN) ? *(const float4*)(src + ((size_t)1 << 18)) : fz;
          float4 f2 = (c0 + 2 < NCIN) ? *(const float4*)(src + ((size_t)2 << 18)) : fz;
          float4 f3 = (c0 + 3 < NCIN) ? *(const float4*)(src + ((size_t)3 << 18)) : fz;
          float4 f4 = (c0 + 4 < NCIN) ? *(const float4*)(src + ((size_t)4 << 18)) : fz;
          float4 f5 = (c0 + 5 < NCIN) ? *(const float4*)(src + ((size_t)5 << 18)) : fz;
          float4 f6 = (c0 + 6 < NCIN) ? *(const float4*)(src + ((size_t)6 << 18)) : fz;
          float4 f7 = (c0 + 7 < NCIN) ? *(const float4*)(src + ((size_t)7 << 18)) : fz;
          uint* dst = &xs[((yy * LCOLS) + (xg << 2)) << 2];
          uint4 u;
          u.x = pack_f16x2(f0.x, f1.x); u.y = pack_f16x2(f2.x, f3.x);
          u.z = pack_f16x2(f4.x, f5.x); u.w = pack_f16x2(f6.x, f7.x);
          *(uint4*)(dst + 0) = u;
          u.x = pack_f16x2(f0.y, f1.y); u.y = pack_f16x2(f2.y, f3.y);
          u.z = pack_f16x2(f4.y, f5.y); u.w = pack_f16x2(f6.y, f7.y);
          *(uint4*)(dst + 4) = u;
          u.x = pack_f16x2(f0.z, f1.z); u.y = pack_f16x2(f2.z, f3.z);
          u.z = pack_f16x2(f4.z, f5.z); u.w = pack_f16x2(f6.z, f7.z);
          *(uint4*)(dst + 8) = u;
          u.x = pack_f16x2(f0.w, f1.w); u.y = pack_f16x2(f2.w, f3.w);
          u.z = pack_f16x2(f4.w, f5.w); u.w = pack_f16x2(f6.w, f7.w);
          *(uint4*)(dst + 12) = u;
        }
      } else {
        for (int e = tid; e < LROWS * 12; e += 256) {
          int yy = e / 12, xg = e - yy * 12;
          int gy = h0 - 6 + yy;
          uint* dst = &xs[((yy * LCOLS) + (xg << 2)) << 2];
#pragma unroll
          for (int p = 0; p < 4; p++) {
            int gx = w0 - 8 + (xg << 2) + p;
            bool in = ((unsigned)gy < (unsigned)HW) && ((unsigned)gx < (unsigned)HW);
            float v[8];
#pragma unroll
            for (int q = 0; q < 8; q++) {
              v[q] = (in && (c0 + q < NCIN))
                   ? x[(((size_t)(bz * NCIN + c0 + q)) << 18) + (size_t)gy * HW + gx]
                   : 0.f;
            }
            uint4 u;
            u.x = pack_f16x2(v[0], v[1]); u.y = pack_f16x2(v[2], v[3]);
            u.z = pack_f16x2(v[4], v[5]); u.w = pack_f16x2(v[6], v[7]);
            *(uint4*)(dst + (p << 2)) = u;
          }
        }
      }
      __syncthreads();

      // A fragments for this (g, cb): 7 steps x b128 per lane (L2-resident)
      const uint4* wp4 = ((const uint4*)wA) + (size_t)((g * NCB + cb) * NSTEP) * 64 + lane;
      f16x8 af[7];
#pragma unroll
      for (int s = 0; s < 7; s++)
        af[s] = __builtin_bit_cast(f16x8, wp4[(size_t)s * 64]);

#pragma unroll
      for (int nt = 0; nt < 8; nt++) {
        const int base_dw = (((6 + (wv << 2) + (nt >> 1)) * LCOLS)
                           + (8 + ((nt & 1) << 4) + col)) << 2;
        f32x4 a = acc[nt];
#pragma unroll
        for (int s = 0; s < 7; s++) {
          uint4 t = *(const uint4*)&xs[base_dw + stepoff[s]];
          f16x8 bf = __builtin_bit_cast(f16x8, t);
          a = __builtin_amdgcn_mfma_f32_16x16x32_f16(af[s], bf, a, 0, 0, 0);
        }
        acc[nt] = a;
      }
    }

    // epilogue for group g: D row (kg*4+r) = oc slot, col = pixel
    const float* bp = (g == 0) ? bias1 : (g == 1) ? bias2 : bias3;
    float bsel[4];
#pragma unroll
    for (int r = 0; r < 4; r++) {
      int slot = (kg << 2) + r;
      bsel[r] = (slot < 6) ? bp[slot] : 0.f;
    }
#pragma unroll
    for (int nt = 0; nt < 8; nt++) {
      const int y = h0 + (wv << 2) + (nt >> 1);
      const int xx = w0 + ((nt & 1) << 4) + col;
      const size_t pix = (size_t)y * HW + xx;
#pragma unroll
      for (int r = 0; r < 4; r++) {
        int slot = (kg << 2) + r;
        if (slot < 6) {
          int ch = 36 + g * 6 + slot;
          out[(((size_t)(bz * 55 + ch)) << 18) + pix] = fmaxf(acc[nt][r] + bsel[r], 0.f);
        }
      }
    }
  }
}

__global__ __launch_bounds__(256) void cellsum_kernel(
    const float* __restrict__ out, const int* __restrict__ row_seg,
    const int* __restrict__ col_seg, const float* __restrict__ wsum,
    const float* __restrict__ wb, float* __restrict__ S)
{
  __shared__ float part[40];
  const int tid = threadIdx.x;
  const int h = blockIdx.y;
  const int w = blockIdx.x * 256 + tid;
  if (tid < 40) part[tid] = 0.f;
  __syncthreads();
  float st = 0.f, sb = 0.f;
  const size_t pix = (size_t)h * HW + w;
#pragma unroll
  for (int b = 0; b < NB; b++)
#pragma unroll
    for (int k = 0; k < 18; k++) {
      float v = out[(((size_t)(b * 55 + 36 + k)) << 18) + pix];
      st = fmaf(wsum[k], v, st);
      sb = fmaf(wb[k], v, sb);
    }
  int cs = col_seg[w];
  atomicAdd(&part[cs * 2], st);
  atomicAdd(&part[cs * 2 + 1], sb);
  __syncthreads();
  if (tid < 20) {
    int cell = row_seg[h] * 20 + tid;
    atomicAdd(&S[cell * 2], part[tid * 2]);
    atomicAdd(&S[cell * 2 + 1], part[tid * 2 + 1]);
  }
}

__global__ __launch_bounds__(1024) void finalize_kernel(
    const int* __restrict__ row_seg, const int* __restrict__ col_seg,
    const float* __restrict__ S, const float* __restrict__ btsum,
    const float* __restrict__ bb, float* __restrict__ tm,
    float* __restrict__ sbm, float* __restrict__ out)
{
  __shared__ int rowcnt[30], colcnt[20];
  const int t = threadIdx.x;
  if (t < 30) rowcnt[t] = 0;
  if (t >= 32 && t < 52) colcnt[t - 32] = 0;
  __syncthreads();
  if (t < 512) atomicAdd(&rowcnt[row_seg[t]], 1);
  else atomicAdd(&colcnt[col_seg[t - 512]], 1);
  __syncthreads();
  if (t < 600) {
    int r = t / 20, c = t - r * 20;
    float cnt = (float)(rowcnt[r] * colcnt[c]);
    float topm = S[2 * t] / (cnt * 144.f) + btsum[0] * (1.f / 36.f);
    float botm = S[2 * t + 1] / (cnt * 4.f) + bb[0];
    tm[t] = topm;
    float s = 1.f / (1.f + expf(-botm));
    sbm[t] = s;
#pragma unroll
    for (int b = 0; b < 4; b++) out[OUTX_SIZE + b * 600 + t] = s;
  }
}

__global__ __launch_bounds__(256) void fill_kernel(
    const int* __restrict__ row_seg, const int* __restrict__ col_seg,
    const float* __restrict__ tm, const float* __restrict__ sbm,
    float* __restrict__ out)
{
  const int idx = blockIdx.x * 256 + threadIdx.x;  // < 1048576
  const int b = idx >> 18;
  const int hw = idx & (NPIX - 1);
  const int h = hw >> 9, w = hw & 511;
  const int cell = row_seg[h] * 20 + col_seg[w];
  const float tmv = tm[cell], sbv = sbm[cell];
  const size_t base = (((size_t)(b * 55)) << 18) + hw;
#pragma unroll
  for (int ch = 0; ch < 36; ch++) out[base + ((size_t)ch << 18)] = tmv;
  out[base + ((size_t)54 << 18)] = sbv;
}

extern "C" void kernel_launch(void* const* d_in, const int* in_sizes, int n_in,
                              void* d_out, int out_size, void* d_ws, size_t ws_size,
                              hipStream_t stream) {
  const float* x       = (const float*)d_in[0];
  const int*   row_seg = (const int*)d_in[1];
  const int*   col_seg = (const int*)d_in[2];
  const float* w1 = (const float*)d_in[3];
  const float* b1 = (const float*)d_in[4];
  const float* w2 = (const float*)d_in[5];
  const float* b2 = (const float*)d_in[6];
  const float* w3 = (const float*)d_in[7];
  const float* b3 = (const float*)d_in[8];
  const float* wt = (const float*)d_in[9];
  const float* bt = (const float*)d_in[10];
  const float* wb = (const float*)d_in[11];
  const float* bb = (const float*)d_in[12];
  float* out = (float*)d_out;
  float* ws  = (float*)d_ws;

  prep_kernel<<<1, 1024, 0, stream>>>(w1, w2, w3, wt, bt, ws);

  dim3 g1(HW / BX, HW / BY, NB);
  conv_kernel<<<g1, 256, 0, stream>>>(x, (const uint*)(ws + WA_OFF),
                                      b1, b2, b3, out);

  dim3 g2(HW / 256, HW);
  cellsum_kernel<<<g2, 256, 0, stream>>>(out, row_seg, col_seg,
                                         ws + WSUM_OFF, wb, ws + S_OFF);

  finalize_kernel<<<1, 1024, 0, stream>>>(row_seg, col_seg, ws + S_OFF,
                                          ws + BTSUM_OFF, bb,
                                          ws + TM_OFF, ws + SBM_OFF, out);

  fill_kernel<<<NB * NPIX / 256, 256, 0, stream>>>(row_seg, col_seg,
                                                   ws + TM_OFF, ws + SBM_OFF, out);
}

// Round 3
// 678.419 us; speedup vs baseline: 1.3866x; 1.3866x over previous
//
#include <hip/hip_runtime.h>
#include <math.h>

#define HW 512
#define NPIX (HW*HW)            // 262144
#define NB 4
#define NCIN 55
#define OUTX_SIZE (NB*55*NPIX)  // 57671680

// ws layout (float/uint offsets)
#define WA_OFF 0          // 37632 uints: [3 g][7 cb][7 step][64 lane][4] f16x2
#define WSUM_OFF 37632    // 18
#define BTSUM_OFF 37650   // 1
#define S_OFF 37664       // 1200: [600][2]
#define TM_OFF 38864      // 600
#define SBM_OFF 39464     // 600

#define BY 16              // output rows per block
#define BX 32              // output cols per block
#define LROWS 28           // BY + 12 halo
#define LCOLS 48           // used cols (x window [w0-8, w0+40))
#define LSTRIDE 49         // LDS row stride in 16B cells (bank-phase rotate)
#define CELLS (LROWS*LSTRIDE)   // 1372 real cells
#define LDSC 1536          // staged cells incl dummy pad (24 wave-loads x 64)
#define NSTEP 7            // K-steps per (g, cb): 28 tap slots (25 real)
#define NCB 7              // channel-blocks of 8 (56 slots, 55 real)

// prepacked X16: per batch b, region = out + (b*55)<<18 floats, layout
// [cb 7][py 524][px 528] cells of 16B (8 f16 channels); py=gy+6, px=gx+8,
// zero outside the 512x512 image.
#define PH 524
#define PW 528
#define CBBYTES (PH*PW*16)  // 4,426,752

typedef _Float16 half2v __attribute__((ext_vector_type(2)));
typedef __attribute__((ext_vector_type(8))) _Float16 f16x8;
typedef __attribute__((ext_vector_type(4))) float f32x4;

__device__ __forceinline__ uint pack_f16x2(float a, float b) {
  return __builtin_bit_cast(uint, __builtin_amdgcn_cvt_pkrtz(a, b));
}

__device__ __forceinline__ void gload16(const void* g, void* l) {
  __builtin_amdgcn_global_load_lds(
      (const __attribute__((address_space(1))) void*)g,
      (__attribute__((address_space(3))) void*)l, 16, 0, 0);
}

// Weight A-fragments for mfma_f32_16x16x32_f16, per (g, cb, step):
// lane l holds A[row = l&15][k = (l>>4)*8 + j], j=0..7
//   row = oc slot (0..5 used), tap = step*4 + (l>>4), ch = cb*8 + j
__global__ __launch_bounds__(1024) void prep_kernel(
    const float* __restrict__ w1, const float* __restrict__ w2, const float* __restrict__ w3,
    const float* __restrict__ wt, const float* __restrict__ bt,
    float* __restrict__ ws)
{
  const int t = threadIdx.x;
  uint* wp = (uint*)(ws + WA_OFF);
  for (int e = t; e < 3 * NCB * NSTEP * 64 * 4; e += 1024) {
    int u = e & 3;
    int rest = e >> 2;
    int lane = rest & 63;
    int idx = rest >> 6;        // (g*7 + cb)*7 + step
    int step = idx % 7;
    int cbg = idx / 7;
    int cb = cbg % 7;
    int g = cbg / 7;
    int oc = lane & 15;
    int kg = lane >> 4;
    int tap = step * 4 + kg;
    int c = cb * 8 + 2 * u;
    const float* wsrc = (g == 0) ? w1 : (g == 1) ? w2 : w3;
    float lo = 0.f, hi = 0.f;
    if (oc < 6 && tap < 25) {
      if (c < NCIN)     lo = wsrc[(oc * NCIN + c) * 25 + tap];
      if (c + 1 < NCIN) hi = wsrc[(oc * NCIN + c + 1) * 25 + tap];
    }
    wp[e] = pack_f16x2(lo, hi);
  }
  if (t < 18) {
    float s = 0.f;
    for (int o = 0; o < 36; o++) s += wt[o * 18 + t];
    ws[WSUM_OFF + t] = s;
  }
  if (t == 18) {
    float s = 0.f;
    for (int o = 0; o < 36; o++) s += bt[o];
    ws[BTSUM_OFF] = s;
  }
  for (int e = t; e < 1200; e += 1024) ws[S_OFF + e] = 0.f;
}

// x f32 -> padded f16 8-channel cells in the out[ch 0..35] scratch region.
__global__ __launch_bounds__(256) void prepack_kernel(
    const float* __restrict__ x, float* __restrict__ out)
{
  const uint idx = blockIdx.x * 256 + threadIdx.x;   // < 4*7*524*528 = 7,746,816
  const uint pw = idx % PW;
  const uint r1 = idx / PW;
  const uint py = r1 % PH;
  const uint r2 = r1 / PH;
  const uint cb = r2 % 7;
  const uint b  = r2 / 7;
  const int gy = (int)py - 6, gx = (int)pw - 8;
  const bool in = ((unsigned)gy < (unsigned)HW) && ((unsigned)gx < (unsigned)HW);
  const int c0 = cb * 8;
  float v[8];
#pragma unroll
  for (int q = 0; q < 8; q++) {
    v[q] = (in && (c0 + q < NCIN))
         ? x[(((size_t)(b * NCIN + c0 + q)) << 18) + (size_t)gy * HW + gx]
         : 0.f;
  }
  uint4 u;
  u.x = pack_f16x2(v[0], v[1]); u.y = pack_f16x2(v[2], v[3]);
  u.z = pack_f16x2(v[4], v[5]); u.w = pack_f16x2(v[6], v[7]);
  char* dst = (char*)(out + ((size_t)(b * 55) << 18))
            + (size_t)cb * CBBYTES + ((size_t)py * PW + pw) * 16;
  *(uint4*)dst = u;
}

// Implicit-GEMM conv, cb-outer / g-inner, double-buffered async LDS staging.
// Per cb: issue 6 global_load_lds (16B/lane) for cb+1, compute 3 g x 8 nt x 7
// steps of mfma_f32_16x16x32_f16 on cb, one __syncthreads drain.
__global__ __launch_bounds__(256, 2) void conv_kernel(
    const uint* wA, const float* bias1, const float* bias2,
    const float* bias3, float* out)
{
  __shared__ uint xs[2 * LDSC * 4];   // 49152 B (2 buffers x 1536 cells x 16B)
  const int tid = threadIdx.x;
  const int lane = tid & 63;
  const int wv = tid >> 6;          // wave 0..3 -> rows wv*4 .. wv*4+3
  const int h0 = blockIdx.y * BY, w0 = blockIdx.x * BX;
  const int bz = blockIdx.z;
  const int col = lane & 15;        // B/D: pixel column within n-tile
  const int kg  = lane >> 4;        // k-group: tap = step*4+kg ; D row base kg*4

  const char* xb = (const char*)out + (((size_t)(bz * 55)) << 20);  // scratch X16
  const uint4* wA4 = (const uint4*)wA;

  // per-lane staging source offsets (6 wave-loads/wave, dummy-clamped)
  uint voff[6];
#pragma unroll
  for (int t = 0; t < 6; t++) {
    int l = (wv * 6 + t) * 64 + lane;
    if (l > CELLS - 1) l = CELLS - 1;
    int row = l / LSTRIDE;
    int c = l - row * LSTRIDE;
    if (c > LCOLS - 1) c = LCOLS - 1;
    voff[t] = (uint)(((h0 + row) * PW) + (w0 + c)) * 16u;
  }

  // tap spatial shifts (dword offsets), per g and step; padded taps -> 0
  int so[3][7];
#pragma unroll
  for (int g = 0; g < 3; g++) {
#pragma unroll
    for (int s = 0; s < 7; s++) {
      int tap = s * 4 + kg;
      int dr = 0, dc = 0;
      if (tap < 25) { int q5 = tap / 5; dr = q5 - 2; dc = tap - q5 * 5 - 2; }
      so[g][s] = ((dr * LSTRIDE + dc) * (g + 1)) << 2;
    }
  }

  f32x4 acc[3][8];
#pragma unroll
  for (int g = 0; g < 3; g++)
#pragma unroll
    for (int nt = 0; nt < 8; nt++) acc[g][nt] = (f32x4){0.f, 0.f, 0.f, 0.f};

  // prologue: stage cb=0 into buffer 0
  {
    const char* sb = xb;
    uint* db = xs;
#pragma unroll
    for (int t = 0; t < 6; t++)
      gload16(sb + voff[t], (char*)db + ((wv * 6 + t) * 1024));
  }
  __syncthreads();

  int cur = 0;
#pragma unroll 1
  for (int cb = 0; cb < NCB; cb++) {
    if (cb < NCB - 1) {
      const char* sb = xb + (size_t)(cb + 1) * CBBYTES;
      uint* db = xs + (cur ^ 1) * (LDSC * 4);
#pragma unroll
      for (int t = 0; t < 6; t++)
        gload16(sb + voff[t], (char*)db + ((wv * 6 + t) * 1024));
    }
    const uint* xsb = xs + cur * (LDSC * 4);
#pragma unroll
    for (int g = 0; g < 3; g++) {
      const uint4* wp4 = wA4 + (size_t)((g * NCB + cb) * NSTEP) * 64 + lane;
      f16x8 af[7];
#pragma unroll
      for (int s = 0; s < 7; s++)
        af[s] = __builtin_bit_cast(f16x8, wp4[(size_t)s * 64]);
#pragma unroll
      for (int nt = 0; nt < 8; nt++) {
        const int bd = (((6 + (wv << 2) + (nt >> 1)) * LSTRIDE)
                       + (8 + ((nt & 1) << 4) + col)) << 2;
        f32x4 a = acc[g][nt];
#pragma unroll
        for (int s = 0; s < 7; s++) {
          uint4 tv = *(const uint4*)&xsb[bd + so[g][s]];
          a = __builtin_amdgcn_mfma_f32_16x16x32_f16(
                af[s], __builtin_bit_cast(f16x8, tv), a, 0, 0, 0);
        }
        acc[g][nt] = a;
      }
    }
    __syncthreads();   // drains staging vmcnt + barrier
    cur ^= 1;
  }

  // epilogue: D row (kg*4+r) = oc slot, col = pixel
#pragma unroll
  for (int g = 0; g < 3; g++) {
    const float* bp = (g == 0) ? bias1 : (g == 1) ? bias2 : bias3;
    float bsel[4];
#pragma unroll
    for (int r = 0; r < 4; r++) {
      int slot = (kg << 2) + r;
      bsel[r] = (slot < 6) ? bp[slot] : 0.f;
    }
#pragma unroll
    for (int nt = 0; nt < 8; nt++) {
      const int y = h0 + (wv << 2) + (nt >> 1);
      const int xx = w0 + ((nt & 1) << 4) + col;
      const size_t pix = (size_t)y * HW + xx;
#pragma unroll
      for (int r = 0; r < 4; r++) {
        int slot = (kg << 2) + r;
        if (slot < 6) {
          int ch = 36 + g * 6 + slot;
          out[(((size_t)(bz * 55 + ch)) << 18) + pix] =
              fmaxf(acc[g][nt][r] + bsel[r], 0.f);
        }
      }
    }
  }
}

__global__ __launch_bounds__(256) void cellsum_kernel(
    const float* __restrict__ out, const int* __restrict__ row_seg,
    const int* __restrict__ col_seg, const float* __restrict__ wsum,
    const float* __restrict__ wb, float* __restrict__ S)
{
  __shared__ float part[40];
  const int tid = threadIdx.x;
  const int h = blockIdx.y;
  const int w = blockIdx.x * 256 + tid;
  if (tid < 40) part[tid] = 0.f;
  __syncthreads();
  float st = 0.f, sb = 0.f;
  const size_t pix = (size_t)h * HW + w;
#pragma unroll
  for (int b = 0; b < NB; b++)
#pragma unroll
    for (int k = 0; k < 18; k++) {
      float v = out[(((size_t)(b * 55 + 36 + k)) << 18) + pix];
      st = fmaf(wsum[k], v, st);
      sb = fmaf(wb[k], v, sb);
    }
  int cs = col_seg[w];
  atomicAdd(&part[cs * 2], st);
  atomicAdd(&part[cs * 2 + 1], sb);
  __syncthreads();
  if (tid < 20) {
    int cell = row_seg[h] * 20 + tid;
    atomicAdd(&S[cell * 2], part[tid * 2]);
    atomicAdd(&S[cell * 2 + 1], part[tid * 2 + 1]);
  }
}

__global__ __launch_bounds__(1024) void finalize_kernel(
    const int* __restrict__ row_seg, const int* __restrict__ col_seg,
    const float* __restrict__ S, const float* __restrict__ btsum,
    const float* __restrict__ bb, float* __restrict__ tm,
    float* __restrict__ sbm, float* __restrict__ out)
{
  __shared__ int rowcnt[30], colcnt[20];
  const int t = threadIdx.x;
  if (t < 30) rowcnt[t] = 0;
  if (t >= 32 && t < 52) colcnt[t - 32] = 0;
  __syncthreads();
  if (t < 512) atomicAdd(&rowcnt[row_seg[t]], 1);
  else atomicAdd(&colcnt[col_seg[t - 512]], 1);
  __syncthreads();
  if (t < 600) {
    int r = t / 20, c = t - r * 20;
    float cnt = (float)(rowcnt[r] * colcnt[c]);
    float topm = S[2 * t] / (cnt * 144.f) + btsum[0] * (1.f / 36.f);
    float botm = S[2 * t + 1] / (cnt * 4.f) + bb[0];
    tm[t] = topm;
    float s = 1.f / (1.f + expf(-botm));
    sbm[t] = s;
#pragma unroll
    for (int b = 0; b < 4; b++) out[OUTX_SIZE + b * 600 + t] = s;
  }
}

__global__ __launch_bounds__(256) void fill_kernel(
    const int* __restrict__ row_seg, const int* __restrict__ col_seg,
    const float* __restrict__ tm, const float* __restrict__ sbm,
    float* __restrict__ out)
{
  const int idx = blockIdx.x * 256 + threadIdx.x;  // < 262144 (4 px / thread)
  const int b = idx >> 16;
  const int p4 = idx & 65535;
  const int h = p4 >> 7, w = (p4 & 127) << 2;
  const int rs = row_seg[h] * 20;
  float4 tmv, sbv;
  {
    int c0 = rs + col_seg[w + 0];
    int c1 = rs + col_seg[w + 1];
    int c2 = rs + col_seg[w + 2];
    int c3 = rs + col_seg[w + 3];
    tmv.x = tm[c0]; tmv.y = tm[c1]; tmv.z = tm[c2]; tmv.w = tm[c3];
    sbv.x = sbm[c0]; sbv.y = sbm[c1]; sbv.z = sbm[c2]; sbv.w = sbm[c3];
  }
  const size_t hw = (size_t)h * HW + w;
  float* base = out + (((size_t)(b * 55)) << 18) + hw;
#pragma unroll
  for (int ch = 0; ch < 36; ch++) *(float4*)(base + ((size_t)ch << 18)) = tmv;
  *(float4*)(base + ((size_t)54 << 18)) = sbv;
}

extern "C" void kernel_launch(void* const* d_in, const int* in_sizes, int n_in,
                              void* d_out, int out_size, void* d_ws, size_t ws_size,
                              hipStream_t stream) {
  const float* x       = (const float*)d_in[0];
  const int*   row_seg = (const int*)d_in[1];
  const int*   col_seg = (const int*)d_in[2];
  const float* w1 = (const float*)d_in[3];
  const float* b1 = (const float*)d_in[4];
  const float* w2 = (const float*)d_in[5];
  const float* b2 = (const float*)d_in[6];
  const float* w3 = (const float*)d_in[7];
  const float* b3 = (const float*)d_in[8];
  const float* wt = (const float*)d_in[9];
  const float* bt = (const float*)d_in[10];
  const float* wb = (const float*)d_in[11];
  const float* bb = (const float*)d_in[12];
  float* out = (float*)d_out;
  float* ws  = (float*)d_ws;

  prep_kernel<<<1, 1024, 0, stream>>>(w1, w2, w3, wt, bt, ws);

  prepack_kernel<<<(NB * 7 * PH * PW) / 256, 256, 0, stream>>>(x, out);

  dim3 g1(HW / BX, HW / BY, NB);
  conv_kernel<<<g1, 256, 0, stream>>>((const uint*)(ws + WA_OFF),
                                      b1, b2, b3, out);

  dim3 g2(HW / 256, HW);
  cellsum_kernel<<<g2, 256, 0, stream>>>(out, row_seg, col_seg,
                                         ws + WSUM_OFF, wb, ws + S_OFF);

  finalize_kernel<<<1, 1024, 0, stream>>>(row_seg, col_seg, ws + S_OFF,
                                          ws + BTSUM_OFF, bb,
                                          ws + TM_OFF, ws + SBM_OFF, out);

  fill_kernel<<<NB * NPIX / 1024, 256, 0, stream>>>(row_seg, col_seg,
                                                    ws + TM_OFF, ws + SBM_OFF, out);
}